// Round 13
// baseline (635.036 us; speedup 1.0000x reference)
//
#include <hip/hip_runtime.h>
#include <hip/hip_bf16.h>

// Problem constants (fixed by the reference)
#define BB 1024
#define NN 512
#define MI 512
#define ME 16
#define ALPHA 0.05f
#define ADMM_IT 15
#define NS_CHEAP 4   // X1 direct + 4 single-plane pairs + 2 hi/lo pairs = 7 NS iters
                     // E0=0.905 -> E5 = max(0.041, bf16-noise floor ~0.09);
                     // precise pair1: ~8e-3, pair2: ~6e-5 -> z-shift ~2e-4 (invisible).
                     // (round 12 lesson: bf16 X-rounding floors E at ~0.09, not 1e-2 —
                     //  one precise pair left absmax at 0.078, 92% of threshold)

typedef __attribute__((ext_vector_type(8))) short short8;
typedef __attribute__((ext_vector_type(4))) float float4v;

__device__ inline short f2bf(float v) {
    __hip_bfloat16 b = __float2bfloat16(v);
    return *reinterpret_cast<short*>(&b);
}
__device__ inline float bf2f(short s) {
    __hip_bfloat16 b = *reinterpret_cast<__hip_bfloat16*>(&s);
    return __bfloat162float(b);
}
__device__ inline void split_store(float v, short* __restrict__ hi, short* __restrict__ lo, size_t idx) {
    short h = f2bf(v);
    hi[idx] = h;
    lo[idx] = f2bf(v - bf2f(h));
}

// ---------------- dtype auto-detect ----------------
__global__ void detect_dtype_k(const unsigned short* __restrict__ g_raw,
                               float* __restrict__ flag) {
    __shared__ int cnt;
    int tid = threadIdx.x;
    if (tid == 0) cnt = 0;
    __syncthreads();
    int local = 0;
    for (int i = tid; i < 8192; i += 256) {
        int e = (g_raw[i] >> 7) & 0xFF;
        if (e >= 0x83) local++;
    }
    atomicAdd(&cnt, local);
    __syncthreads();
    if (tid == 0) flag[0] = (cnt < 64) ? 1.0f : 0.0f;  // 1 => bf16 inputs
}

// ---------------- fused ingest (also zeroes rs) ----------------
__global__ void ingest_all_k(const void* __restrict__ c_raw, const void* __restrict__ G_raw,
                             const void* __restrict__ h_raw, const void* __restrict__ A_raw,
                             const void* __restrict__ b_raw,
                             float* __restrict__ cF, short* __restrict__ xh, short* __restrict__ xl,
                             float* __restrict__ GF, short* __restrict__ GFh, short* __restrict__ GFl,
                             float* __restrict__ hF, float* __restrict__ AF, float* __restrict__ bF,
                             float* __restrict__ rs, const float* __restrict__ flag) {
    int i = blockIdx.x * 256 + threadIdx.x;
    bool isbf = flag[0] > 0.5f;
    #define RD(p, idx) (isbf ? __bfloat162float(((const __hip_bfloat16*)(p))[idx]) : ((const float*)(p))[idx])
    if (i < BB * NN) { float v = RD(c_raw, i); cF[i] = v; split_store(v, xh, xl, i); }
    if (i < MI * NN) { float v = RD(G_raw, i); GF[i] = v; split_store(v, GFh, GFl, i); }
    if (i < MI)      hF[i] = RD(h_raw, i);
    if (i < ME * NN) AF[i] = RD(A_raw, i);
    if (i < ME)      bF[i] = RD(b_raw, i);
    if (i < NN)      rs[i] = 0.f;
    #undef RD
}

// transpose 512x512 f32 -> bf16 hi/lo planes
__global__ void transpose_split_k(const float* __restrict__ src,
                                  short* __restrict__ dh, short* __restrict__ dl) {
    __shared__ float t[32][33];
    int bx = blockIdx.x * 32, by = blockIdx.y * 32;
    int tx = threadIdx.x & 31, ty0 = threadIdx.x >> 5;
    for (int i = ty0; i < 32; i += 8) t[i][tx] = src[(by + i) * 512 + bx + tx];
    __syncthreads();
    for (int i = ty0; i < 32; i += 8)
        split_store(t[tx][i], dh, dl, (size_t)(bx + i) * 512 + by + tx);
}

// X1 = 2c0*I - c0^2*M  (bf16-hi only; NS self-corrects), c0 from Gershgorin rs
__global__ void initX1_k(const float* __restrict__ rs, const float* __restrict__ Mm,
                         short* __restrict__ X1h) {
    int ln = threadIdx.x & 63;
    float mx = 0.f;
    #pragma unroll
    for (int i = 0; i < 8; ++i) mx = fmaxf(mx, rs[ln + i * 64]);
    for (int off = 32; off; off >>= 1) mx = fmaxf(mx, __shfl_down(mx, off));
    float c0 = 2.0f / (1.0f + __shfl(mx, 0));
    #pragma unroll
    for (int j = 0; j < 4; ++j) {
        int idx = blockIdx.x * 1024 + j * 256 + threadIdx.x;
        int r = idx >> 9, cc = idx & 511;
        float v = -c0 * c0 * Mm[idx] + ((r == cc) ? 2.0f * c0 : 0.f);
        X1h[idx] = f2bf(v);
    }
}

// fused Sm = A Y (16x16) then Si = inv(Sm), one block
__global__ void sm_inv_k(const float* __restrict__ AF, const float* __restrict__ Y,
                         float* __restrict__ Si) {
    __shared__ float Sm[256];
    int i = threadIdx.x >> 4, j = threadIdx.x & 15;
    float s = 0.f;
    #pragma unroll 8
    for (int k = 0; k < 512; ++k) s += AF[i * 512 + k] * Y[k * 16 + j];
    Sm[i * 16 + j] = s;
    __syncthreads();
    if (threadIdx.x < 64) {
        int r = threadIdx.x;
        float a[16], bI[16];
        #pragma unroll
        for (int jj = 0; jj < 16; ++jj) {
            a[jj]  = (r < 16) ? Sm[r * 16 + jj] : 0.f;
            bI[jj] = (r < 16 && jj == r) ? 1.f : 0.f;
        }
        for (int k = 0; k < 16; ++k) {
            float pa[16], pb[16];
            #pragma unroll
            for (int jj = 0; jj < 16; ++jj) { pa[jj] = __shfl(a[jj], k); pb[jj] = __shfl(bI[jj], k); }
            float inv = 1.0f / pa[k];
            if (r == k) {
                #pragma unroll
                for (int jj = 0; jj < 16; ++jj) { a[jj] = pa[jj] * inv; bI[jj] = pb[jj] * inv; }
            } else {
                float f = a[k] * inv;
                #pragma unroll
                for (int jj = 0; jj < 16; ++jj) {
                    a[jj]  = fmaf(-f, pa[jj], a[jj]);
                    bI[jj] = fmaf(-f, pb[jj], bI[jj]);
                }
            }
        }
        if (r < 16)
            #pragma unroll
            for (int jj = 0; jj < 16; ++jj) Si[r * 16 + jj] = bI[jj];
    }
}

// ---------------- skinny ME-dim kernels ----------------
__global__ void Y_k(const float* __restrict__ Minv, const float* __restrict__ AF,
                    float* __restrict__ Y) {
    int m = blockIdx.x;
    int wv = threadIdx.x >> 6, lane = threadIdx.x & 63;
    float mv[8];
    #pragma unroll
    for (int i = 0; i < 8; ++i) mv[i] = Minv[m * 512 + lane + i * 64];
    #pragma unroll
    for (int jj = 0; jj < 4; ++jj) {
        int j = wv * 4 + jj;
        float s = 0.f;
        #pragma unroll
        for (int i = 0; i < 8; ++i) s += mv[i] * AF[j * 512 + lane + i * 64];
        for (int off = 32; off; off >>= 1) s += __shfl_down(s, off);
        if (lane == 0) Y[m * 16 + j] = s;
    }
}

__global__ void T1zb_k(const float* __restrict__ Y, const float* __restrict__ Si,
                       const float* __restrict__ bF, float* __restrict__ T1,
                       float* __restrict__ zb) {
    int m = blockIdx.x * 16 + (threadIdx.x >> 4), j = threadIdx.x & 15;
    float s = 0.f;
    #pragma unroll
    for (int k = 0; k < 16; ++k) s += Y[m * 16 + k] * Si[k * 16 + j];
    T1[m * 16 + j] = s;
    float v = s * bF[j];
    v += __shfl_down(v, 8); v += __shfl_down(v, 4);
    v += __shfl_down(v, 2); v += __shfl_down(v, 1);
    if (j == 0) zb[m] = v;
}

// W1 = Minv - T1 Y^T -> planes only (into Bcat W1 slice)
__global__ void W1_k(const float* __restrict__ Minv, const float* __restrict__ T1,
                     const float* __restrict__ Y,
                     short* __restrict__ W1h, short* __restrict__ W1l) {
    int idx = blockIdx.x * 256 + threadIdx.x;
    int m = idx >> 9, n = idx & 511;
    float s = Minv[idx];
    #pragma unroll
    for (int k = 0; k < 16; ++k) s -= T1[m * 16 + k] * Y[n * 16 + k];
    split_store(s, W1h, W1l, idx);
}

__global__ void g0_k(const float* __restrict__ GF, const float* __restrict__ zb,
                     float* __restrict__ g0) {
    int m = blockIdx.x * 4 + (threadIdx.x >> 6);
    int lane = threadIdx.x & 63;
    float s = 0.f;
    #pragma unroll
    for (int i = 0; i < 8; ++i) s += GF[m * 512 + lane + i * 64] * zb[lane + i * 64];
    for (int off = 32; off; off >>= 1) s += __shfl_down(s, off);
    if (lane == 0) g0[m] = s;
}

// ---------------- pipelined split-bf16 MFMA NT GEMM, K = 512 ----------------
// Tile 16 rows x 64 cols, 4 waves. k-chunk 128, register prefetch of next chunk.
// epi: 0 C=acc (+planes if Chi)    1 C=acc+(m==n), planes, rs row-abs atomics (M build)
//      2 C=2E-acc, planes (NS precise X-step)
//      6 z=acc+E+v1[n]; x'=(1-a)z+a*Xtra; planes            (final z + PGD)
//      7 combo by col-segment: [G | R | W1] -> t0-hi+U=0 | q0=acc+E[n'] | Xtra=acc
//      8 z=acc+E+v1[n]; emit to Out (bf16/f32 per dtf)
//      9 planes only
#define CH 128
#define LDC 136

__global__ __launch_bounds__(256) void mfma_gemm2(
    const short* __restrict__ Ahi, const short* __restrict__ Alo,
    const short* __restrict__ Bhi, const short* __restrict__ Blo,
    float* __restrict__ C, short* __restrict__ Chi, short* __restrict__ Clo,
    const float* __restrict__ E, const float* __restrict__ v1,
    float* __restrict__ U, float* __restrict__ Xtra,
    const float* __restrict__ dtf, void* __restrict__ Out, int epi)
{
    __shared__ short Ash[2][16 * LDC];
    __shared__ short Bsh[2][64 * LDC];
    const int tid = threadIdx.x;
    const int wv = tid >> 6, ln = tid & 63;
    const int quad = ln >> 4, lr = ln & 15;
    const int m0 = blockIdx.y * 16, n0 = blockIdx.x * 64;

    float4v acc1 = {0.f, 0.f, 0.f, 0.f};
    float4v acc2 = {0.f, 0.f, 0.f, 0.f};

    short8 pa[2], pb[8];
    #pragma unroll
    for (int i = 0; i < 2; ++i) {
        int s = tid + 256 * i; int pl = s >> 8, rem = s & 255, row = rem >> 4, oct = rem & 15;
        const short* P = pl ? Alo : Ahi;
        pa[i] = *(const short8*)(P + (size_t)(m0 + row) * 512 + oct * 8);
    }
    #pragma unroll
    for (int i = 0; i < 8; ++i) {
        int s = tid + 256 * i; int pl = s >> 10, rem = s & 1023, row = rem >> 4, oct = rem & 15;
        const short* P = pl ? Blo : Bhi;
        pb[i] = *(const short8*)(P + (size_t)(n0 + row) * 512 + oct * 8);
    }

    for (int c = 0; c < 4; ++c) {
        if (c) __syncthreads();
        #pragma unroll
        for (int i = 0; i < 2; ++i) {
            int s = tid + 256 * i; int pl = s >> 8, rem = s & 255, row = rem >> 4, oct = rem & 15;
            *(short8*)&Ash[pl][row * LDC + oct * 8] = pa[i];
        }
        #pragma unroll
        for (int i = 0; i < 8; ++i) {
            int s = tid + 256 * i; int pl = s >> 10, rem = s & 1023, row = rem >> 4, oct = rem & 15;
            *(short8*)&Bsh[pl][row * LDC + oct * 8] = pb[i];
        }
        __syncthreads();
        if (c + 1 < 4) {
            int kb = (c + 1) * CH;
            #pragma unroll
            for (int i = 0; i < 2; ++i) {
                int s = tid + 256 * i; int pl = s >> 8, rem = s & 255, row = rem >> 4, oct = rem & 15;
                const short* P = pl ? Alo : Ahi;
                pa[i] = *(const short8*)(P + (size_t)(m0 + row) * 512 + kb + oct * 8);
            }
            #pragma unroll
            for (int i = 0; i < 8; ++i) {
                int s = tid + 256 * i; int pl = s >> 10, rem = s & 1023, row = rem >> 4, oct = rem & 15;
                const short* P = pl ? Blo : Bhi;
                pb[i] = *(const short8*)(P + (size_t)(n0 + row) * 512 + kb + oct * 8);
            }
        }
        #pragma unroll
        for (int ks = 0; ks < 4; ++ks) {
            int ko = (ks * 4 + quad) * 8;
            short8 ah = *(const short8*)&Ash[0][lr * LDC + ko];
            short8 al = *(const short8*)&Ash[1][lr * LDC + ko];
            short8 bh = *(const short8*)&Bsh[0][(wv * 16 + lr) * LDC + ko];
            short8 bl = *(const short8*)&Bsh[1][(wv * 16 + lr) * LDC + ko];
            acc1 = __builtin_amdgcn_mfma_f32_16x16x32_bf16(ah, bh, acc1, 0, 0, 0);
            acc2 = __builtin_amdgcn_mfma_f32_16x16x32_bf16(ah, bl, acc2, 0, 0, 0);
            acc2 = __builtin_amdgcn_mfma_f32_16x16x32_bf16(al, bh, acc2, 0, 0, 0);
        }
    }

    // C/D layout: col = lane&15, row = quad*4 + reg
    #pragma unroll
    for (int r = 0; r < 4; ++r) {
        int m = m0 + quad * 4 + r;
        int n = n0 + wv * 16 + lr;
        float a = acc1[r] + acc2[r];
        if (epi == 7) {
            int seg = n0 >> 9;
            int nl = n - (seg << 9);
            size_t idx = (size_t)m * 512 + nl;
            if (seg == 0) {
                float t0 = fminf(v1[nl], a);
                U[idx] = 0.f;
                Chi[idx] = f2bf(t0);     // bf16-only t for the ADMM chain
            } else if (seg == 1) {
                C[idx] = a + E[nl];
            } else {
                Xtra[idx] = a;
            }
            continue;
        }
        size_t idx = (size_t)m * 512 + n;
        if (epi == 0) {
            C[idx] = a;
            if (Chi) split_store(a, Chi, Clo, idx);
        } else if (epi == 1) {
            a += (m == n) ? 1.f : 0.f;
            C[idx] = a;
            split_store(a, Chi, Clo, idx);
            float s = fabsf(a);                      // Gershgorin row-abs partial
            s += __shfl_xor(s, 1); s += __shfl_xor(s, 2);
            s += __shfl_xor(s, 4); s += __shfl_xor(s, 8);
            if (lr == 0) atomicAdd(&U[m], s);        // U carries rs here
        } else if (epi == 2) {
            a = 2.f * E[idx] - a;
            C[idx] = a;
            split_store(a, Chi, Clo, idx);
        } else if (epi == 6) {
            float z = a + E[idx] + v1[n];
            float xp = (1.0f - ALPHA) * z + ALPHA * Xtra[idx];
            split_store(xp, Chi, Clo, idx);
        } else if (epi == 8) {
            float z = a + E[idx] + v1[n];
            if (dtf[0] > 0.5f) ((__hip_bfloat16*)Out)[idx] = __float2bfloat16(z);
            else               ((float*)Out)[idx] = z;
        } else {  // 9: planes only
            split_store(a, Chi, Clo, idx);
        }
    }
}

// ---------------- single-plane bf16 NT GEMM (NS cheap iterations) ------------
// mode 0: Ch = bf16(acc)  (U = X M)
// mode 1: v = 2*bf2f(Eh) - acc; Ch = bf16(v); if Cl: also lo plane + f32 Cf
__global__ __launch_bounds__(256) void sp_gemm_k(
    const short* __restrict__ Ab, const short* __restrict__ Bb,
    const short* __restrict__ Eh, short* __restrict__ Ch,
    short* __restrict__ Cl, float* __restrict__ Cf, int mode)
{
    __shared__ short As[16 * LDC];
    __shared__ short Bs[64 * LDC];
    const int tid = threadIdx.x;
    const int wv = tid >> 6, ln = tid & 63;
    const int quad = ln >> 4, lr = ln & 15;
    const int m0 = blockIdx.y * 16, n0 = blockIdx.x * 64;

    float4v acc1 = {0.f, 0.f, 0.f, 0.f};
    float4v acc2 = {0.f, 0.f, 0.f, 0.f};

    short8 pa, pb[4];
    {
        int row = tid >> 4, oct = tid & 15;
        pa = *(const short8*)(Ab + (size_t)(m0 + row) * 512 + oct * 8);
    }
    #pragma unroll
    for (int i = 0; i < 4; ++i) {
        int s = tid + 256 * i; int row = s >> 4, oct = s & 15;
        pb[i] = *(const short8*)(Bb + (size_t)(n0 + row) * 512 + oct * 8);
    }

    for (int c = 0; c < 4; ++c) {
        if (c) __syncthreads();
        {
            int row = tid >> 4, oct = tid & 15;
            *(short8*)&As[row * LDC + oct * 8] = pa;
        }
        #pragma unroll
        for (int i = 0; i < 4; ++i) {
            int s = tid + 256 * i; int row = s >> 4, oct = s & 15;
            *(short8*)&Bs[row * LDC + oct * 8] = pb[i];
        }
        __syncthreads();
        if (c + 1 < 4) {
            int kb = (c + 1) * CH;
            {
                int row = tid >> 4, oct = tid & 15;
                pa = *(const short8*)(Ab + (size_t)(m0 + row) * 512 + kb + oct * 8);
            }
            #pragma unroll
            for (int i = 0; i < 4; ++i) {
                int s = tid + 256 * i; int row = s >> 4, oct = s & 15;
                pb[i] = *(const short8*)(Bb + (size_t)(n0 + row) * 512 + kb + oct * 8);
            }
        }
        #pragma unroll
        for (int ks = 0; ks < 4; ++ks) {
            int ko = (ks * 4 + quad) * 8;
            short8 a = *(const short8*)&As[lr * LDC + ko];
            short8 b = *(const short8*)&Bs[(wv * 16 + lr) * LDC + ko];
            if (ks & 1) acc2 = __builtin_amdgcn_mfma_f32_16x16x32_bf16(a, b, acc2, 0, 0, 0);
            else        acc1 = __builtin_amdgcn_mfma_f32_16x16x32_bf16(a, b, acc1, 0, 0, 0);
        }
    }

    #pragma unroll
    for (int r = 0; r < 4; ++r) {
        int m = m0 + quad * 4 + r;
        int n = n0 + wv * 16 + lr;
        size_t idx = (size_t)m * 512 + n;
        float a = acc1[r] + acc2[r];
        if (mode == 0) {
            Ch[idx] = f2bf(a);
        } else {
            float v = 2.f * bf2f(Eh[idx]) - a;
            short hh = f2bf(v);
            Ch[idx] = hh;
            if (Cl) {
                Cl[idx] = f2bf(v - bf2f(hh));
                Cf[idx] = v;
            }
        }
    }
}

// ---------------- bf16-single-plane ADMM step GEMM ----------------
__global__ __launch_bounds__(256) void admm_bf16_k(
    const short* __restrict__ Ab, const short* __restrict__ Bb,
    const float* __restrict__ q0, const float* __restrict__ hF,
    float* __restrict__ uB, short* __restrict__ dh, short* __restrict__ dl)
{
    __shared__ short As[16 * LDC];
    __shared__ short Bs[64 * LDC];
    const int tid = threadIdx.x;
    const int wv = tid >> 6, ln = tid & 63;
    const int quad = ln >> 4, lr = ln & 15;
    const int m0 = blockIdx.y * 16, n0 = blockIdx.x * 64;

    float4v acc1 = {0.f, 0.f, 0.f, 0.f};
    float4v acc2 = {0.f, 0.f, 0.f, 0.f};

    short8 pa, pb[4];
    {
        int row = tid >> 4, oct = tid & 15;
        pa = *(const short8*)(Ab + (size_t)(m0 + row) * 512 + oct * 8);
    }
    #pragma unroll
    for (int i = 0; i < 4; ++i) {
        int s = tid + 256 * i; int row = s >> 4, oct = s & 15;
        pb[i] = *(const short8*)(Bb + (size_t)(n0 + row) * 512 + oct * 8);
    }

    for (int c = 0; c < 4; ++c) {
        if (c) __syncthreads();
        {
            int row = tid >> 4, oct = tid & 15;
            *(short8*)&As[row * LDC + oct * 8] = pa;
        }
        #pragma unroll
        for (int i = 0; i < 4; ++i) {
            int s = tid + 256 * i; int row = s >> 4, oct = s & 15;
            *(short8*)&Bs[row * LDC + oct * 8] = pb[i];
        }
        __syncthreads();
        if (c + 1 < 4) {
            int kb = (c + 1) * CH;
            {
                int row = tid >> 4, oct = tid & 15;
                pa = *(const short8*)(Ab + (size_t)(m0 + row) * 512 + kb + oct * 8);
            }
            #pragma unroll
            for (int i = 0; i < 4; ++i) {
                int s = tid + 256 * i; int row = s >> 4, oct = s & 15;
                pb[i] = *(const short8*)(Bb + (size_t)(n0 + row) * 512 + kb + oct * 8);
            }
        }
        #pragma unroll
        for (int ks = 0; ks < 4; ++ks) {
            int ko = (ks * 4 + quad) * 8;
            short8 a = *(const short8*)&As[lr * LDC + ko];
            short8 b = *(const short8*)&Bs[(wv * 16 + lr) * LDC + ko];
            if (ks & 1) acc2 = __builtin_amdgcn_mfma_f32_16x16x32_bf16(a, b, acc2, 0, 0, 0);
            else        acc1 = __builtin_amdgcn_mfma_f32_16x16x32_bf16(a, b, acc1, 0, 0, 0);
        }
    }

    #pragma unroll
    for (int r = 0; r < 4; ++r) {
        int m = m0 + quad * 4 + r;
        int n = n0 + wv * 16 + lr;
        size_t idx = (size_t)m * 512 + n;
        float gz = acc1[r] + acc2[r] + q0[idx];
        float hn = hF[n];
        float w = hn - gz - uB[idx];
        uB[idx] = fmaxf(0.f, -w);
        float t2 = hn - fabsf(w);
        short hh = f2bf(t2);
        dh[idx] = hh;
        if (dl) dl[idx] = f2bf(t2 - bf2f(hh));
    }
}

// ---------------- host launcher ----------------

extern "C" void kernel_launch(void* const* d_in, const int* in_sizes, int n_in,
                              void* d_out, int out_size, void* d_ws, size_t ws_size,
                              hipStream_t stream) {
    const void* c_raw = d_in[0];
    const void* G_raw = d_in[1];
    const void* h_raw = d_in[2];
    const void* A_raw = d_in[3];
    const void* b_raw = d_in[4];

    float* w = (float*)d_ws;
    size_t o = 0;
    auto alloc = [&](size_t n) { float* p = w + o; o += (n + 63) & ~(size_t)63; return p; };

    float* cF  = alloc(BB * NN);
    float* GF  = alloc(MI * NN);
    float* AF  = alloc(ME * NN);
    float* hF  = alloc(MI);
    float* bF  = alloc(ME);
    float* Mm  = alloc(NN * NN);
    float* Xf0 = alloc(NN * NN);
    float* Xf1 = alloc(NN * NN);
    float* Rf  = alloc(MI * NN);
    float* Y   = alloc(NN * ME);
    float* T1  = alloc(NN * ME);
    float* Si  = alloc(ME * ME);
    float* zb  = alloc(NN);
    float* g0  = alloc(MI);
    float* rs  = alloc(NN);
    float* dtf = alloc(16);
    float* q0  = alloc(BB * MI);
    float* xW  = alloc(BB * NN);
    float* uB  = alloc(BB * MI);

    short* sbp = (short*)(w + o);
    size_t so = 0;
    auto allocS = [&](size_t n) { short* p = sbp + so; so += (n + 127) & ~(size_t)127; return p; };

    // Bcat = [G(512) ; R(512) ; W1(512)] x 512, contiguous per plane
    short* Bcat_h = allocS(3 * 512 * 512);
    short* Bcat_l = allocS(3 * 512 * 512);
    short* GFh = Bcat_h;              short* GFl = Bcat_l;
    short* Rh  = Bcat_h + 512 * 512;  short* Rl  = Bcat_l + 512 * 512;
    short* W1h = Bcat_h + 1024 * 512; short* W1l = Bcat_l + 1024 * 512;

    short* GTh = allocS(NN * MI);  short* GTl = allocS(NN * MI);
    short* Mmh = allocS(NN * NN);  short* Mml = allocS(NN * NN);
    short* X0h = allocS(NN * NN);  short* X0l = allocS(NN * NN);
    short* X1h = allocS(NN * NN);  short* X1l = allocS(NN * NN);
    short* Uh  = allocS(NN * NN);  short* Ul  = allocS(NN * NN);
    short* RTh = allocS(NN * MI);  short* RTl = allocS(NN * MI);
    short* Qh  = allocS(MI * MI);  short* Ql  = allocS(MI * MI);
    short* xh  = allocS(BB * NN);  short* xl  = allocS(BB * NN);
    short* tAh = allocS(BB * MI);  short* tAl = allocS(BB * MI);
    short* tBh = allocS(BB * MI);  short* tBl = allocS(BB * MI);

    dim3 blk(256);
    auto cdiv = [](int a, int b) { return (a + b - 1) / b; };
    dim3 gSq(8, 32);    // 512x512 outputs
    dim3 gBt(8, 64);    // 1024x512 outputs
    dim3 gCombo(24, 64);

    detect_dtype_k<<<1, 256, 0, stream>>>((const unsigned short*)G_raw, dtf);
    ingest_all_k<<<cdiv(BB * NN, 256), blk, 0, stream>>>(
        c_raw, G_raw, h_raw, A_raw, b_raw,
        cF, xh, xl, GF, GFh, GFl, hF, AF, bF, rs, dtf);

    // G^T planes
    transpose_split_k<<<dim3(16, 16), blk, 0, stream>>>(GF, GTh, GTl);

    // M = I + G^T G  (f32 + planes + Gershgorin row-abs atomics into rs)
    mfma_gemm2<<<gSq, blk, 0, stream>>>(GTh, GTl, GTh, GTl, Mm, Mmh, Mml,
                                        nullptr, nullptr, rs, nullptr, nullptr, nullptr, 1);

    // X1 = 2c0 I - c0^2 M  (bf16-hi only; skips the first NS pair)
    initX1_k<<<256, blk, 0, stream>>>(rs, Mm, X0h);

    // NS cheap iterations (single-plane): X2..X5; last pair emits hi/lo + f32
    short* XcurH = X0h;
    short* XnxtH = X1h;
    for (int it = 0; it < NS_CHEAP; ++it) {
        bool last = (it == NS_CHEAP - 1);
        sp_gemm_k<<<gSq, blk, 0, stream>>>(XcurH, Mmh, nullptr, Uh, nullptr, nullptr, 0);
        short* nl = last ? ((XnxtH == X0h) ? X0l : X1l) : nullptr;
        float* nf = last ? ((XnxtH == X0h) ? Xf0 : Xf1) : nullptr;
        sp_gemm_k<<<gSq, blk, 0, stream>>>(Uh, XcurH, XcurH, XnxtH, nl, nf, 1);
        short* t = XcurH; XcurH = XnxtH; XnxtH = t;
    }
    // NS_CHEAP=4 even -> X5 in X0h/X0l/Xf0
    // Precise pair 1: U = X5 M; X6 = 2 X5 - U X5  -> Xf1/X1h/X1l
    mfma_gemm2<<<gSq, blk, 0, stream>>>(X0h, X0l, Mmh, Mml, nullptr, Uh, Ul,
                                        nullptr, nullptr, nullptr, nullptr, nullptr, nullptr, 9);
    mfma_gemm2<<<gSq, blk, 0, stream>>>(Uh, Ul, X0h, X0l, Xf1, X1h, X1l,
                                        Xf0, nullptr, nullptr, nullptr, nullptr, nullptr, 2);
    // Precise pair 2: U = X6 M; X7 = 2 X6 - U X6  -> Xf0/X0h/X0l
    mfma_gemm2<<<gSq, blk, 0, stream>>>(X1h, X1l, Mmh, Mml, nullptr, Uh, Ul,
                                        nullptr, nullptr, nullptr, nullptr, nullptr, nullptr, 9);
    mfma_gemm2<<<gSq, blk, 0, stream>>>(Uh, Ul, X1h, X1l, Xf0, X0h, X0l,
                                        Xf1, nullptr, nullptr, nullptr, nullptr, nullptr, 2);
    float* Minv = Xf0;

    // Schur pieces
    Y_k<<<NN, blk, 0, stream>>>(Minv, AF, Y);
    sm_inv_k<<<1, blk, 0, stream>>>(AF, Y, Si);
    T1zb_k<<<NN / 16, blk, 0, stream>>>(Y, Si, bF, T1, zb);
    W1_k<<<NN * NN / 256, blk, 0, stream>>>(Minv, T1, Y, W1h, W1l);

    // R = G W1 (f32 + planes into Bcat R slice)
    mfma_gemm2<<<gSq, blk, 0, stream>>>(GFh, GFl, W1h, W1l, Rf, Rh, Rl,
                                        nullptr, nullptr, nullptr, nullptr, nullptr, nullptr, 0);
    transpose_split_k<<<dim3(16, 16), blk, 0, stream>>>(Rf, RTh, RTl);
    // Q = R G^T (planes; ADMM uses hi only)
    mfma_gemm2<<<gSq, blk, 0, stream>>>(Rh, Rl, GFh, GFl, nullptr, Qh, Ql,
                                        nullptr, nullptr, nullptr, nullptr, nullptr, nullptr, 9);
    g0_k<<<NN / 4, blk, 0, stream>>>(GF, zb, g0);

    // 4 projections (x0 = c, planes already in xh/xl from ingest)
    for (int p = 0; p < 4; ++p) {
        // combo: [t0-init | q0 | xW] in one launch, B = [G;R;W1]
        mfma_gemm2<<<gCombo, blk, 0, stream>>>(xh, xl, Bcat_h, Bcat_l, q0, tAh, tAl,
                                               g0, hF, uB, xW, nullptr, nullptr, 7);
        for (int it = 0; it < ADMM_IT; ++it) {
            const short* sh = (it & 1) ? tBh : tAh;
            short* dh = (it & 1) ? tAh : tBh;
            short* dl = (it == ADMM_IT - 1) ? tBl : nullptr;  // last iter -> lo plane too
            admm_bf16_k<<<gBt, blk, 0, stream>>>(sh, Qh, q0, hF, uB, dh, dl);
        }
        // final z = t R + xW + zb (t in tB hi/lo after 15 iters); PGD split or emit
        if (p < 3) {
            mfma_gemm2<<<gBt, blk, 0, stream>>>(tBh, tBl, RTh, RTl, nullptr, xh, xl,
                                                xW, zb, nullptr, cF, nullptr, nullptr, 6);
        } else {
            mfma_gemm2<<<gBt, blk, 0, stream>>>(tBh, tBl, RTh, RTl, nullptr, nullptr, nullptr,
                                                xW, zb, nullptr, nullptr, dtf, d_out, 8);
        }
    }
}